// Round 5
// baseline (24318.266 us; speedup 1.0000x reference)
//
#include <hip/hip_runtime.h>
#include <cmath>

constexpr int kB = 64, kS = 512, kD = 128, kH = 512, kOut = 24;
constexpr int kBlocks = 256, kThreads = 512;
constexpr size_t kBarOffBytes = (size_t)5 * kB * kH * 4;   // after H0,H1,tmp1

struct Params {
  const float* x;
  const float* w0[4]; const float* b0[4];   // f,i,o,g  [512,640] / [512]
  const float* w1[4]; const float* b1[4];   // f,i,o,g  [512,1024] / [512]
  const float* fc1w; const float* fc1b;
  const float* fc2w; const float* fc2b;
  float* H0;    // 2 buffers [64][512]
  float* H1;    // 2 buffers [64][512]
  float* tmp1;  // [64][512]
  unsigned* flags;  // 256 slots, 64B apart; gen at flags[4096]
  float* out;   // [64][24]
};

__device__ __forceinline__ float sigmoidf_(float v) {
  return 1.0f / (1.0f + expf(-v));
}

// Atomic-free grid barrier (flag/collector):
//  - every block: __threadfence (release) + relaxed agent store flag[bid]=r+1
//  - block 0: threads 0..255 poll flag[tid] >= r+1 in parallel, fence,
//    syncthreads, thread0 publishes gen=r+1
//  - other blocks: thread0 spins on gen >= r+1, fence (acquire)
// Monotone round numbers -> no reset race. No serialized same-line RMWs.
__device__ __forceinline__ void grid_barrier(unsigned* flags, int bid, int tid,
                                             unsigned r) {
  unsigned* gen = flags + 4096;
  __syncthreads();
  if (tid == 0) {
    __threadfence();   // release all block's prior writes (HB via syncthreads)
    __hip_atomic_store(flags + bid * 16, r + 1u, __ATOMIC_RELAXED,
                       __HIP_MEMORY_SCOPE_AGENT);
  }
  if (bid == 0) {
    if (tid < kBlocks) {
      while (__hip_atomic_load(flags + tid * 16, __ATOMIC_RELAXED,
                               __HIP_MEMORY_SCOPE_AGENT) < r + 1u) {
        __builtin_amdgcn_s_sleep(1);
      }
      __threadfence();  // acquire (per observing thread)
    }
    __syncthreads();    // all 256 flags observed
    if (tid == 0) {
      __threadfence();
      __hip_atomic_store(gen, r + 1u, __ATOMIC_RELAXED,
                         __HIP_MEMORY_SCOPE_AGENT);
    }
  } else {
    if (tid == 0) {
      while (__hip_atomic_load(gen, __ATOMIC_RELAXED,
                               __HIP_MEMORY_SCOPE_AGENT) < r + 1u) {
        __builtin_amdgcn_s_sleep(1);
      }
      __threadfence();  // acquire
    }
  }
  __syncthreads();
}

// Block (cgi, bh): cgi=bid>>1 owns hidden cols j0=4*cgi..j0+3 (all 4 gates,
// 16 gate-rows), bh=bid&1 owns batches bh*32..bh*32+31.
// Thread tid = r4*128 + kt*8 + bg  (r4: gate, kt: 16-way k-split, bg: batch grp).
// Chunks are 256 floats wide (128 for the x part); all staging loads issued at
// phase start (regs), chunk weights issued before the ds_write/sync they must
// overlap. k-accumulation order identical to round 4 -> bit-identical result.
__global__ void __launch_bounds__(kThreads, 2)
lstm_persistent(Params p) {
  __shared__ float ub[8320];   // union: u-stage 32x260 | partials 16x520
  __shared__ float gs[512];    // gate preactivations [row(16)][b_local(32)]

  const int tid = threadIdx.x;
  const int bid = blockIdx.x;
  const int cgi = bid >> 1;
  const int bh  = bid & 1;
  const int j0  = cgi * 4;
  const int bbase = bh * 32;

  const int r4 = tid >> 7;
  const int kt = (tid >> 3) & 15;
  const int bg = tid & 7;

  unsigned rnd = 0;

  if (tid < 128) {
    const int jl = tid >> 5, bb = tid & 31;
    const int b = bbase + bb;
    p.H0[kB * kH + b * kH + j0 + jl] = 0.f;
    p.H1[kB * kH + b * kH + j0 + jl] = 0.f;
  }

  float* H0buf[2] = { p.H0, p.H0 + kB * kH };
  float* H1buf[2] = { p.H1, p.H1 + kB * kH };
  float c0 = 0.f, c1 = 0.f;

  grid_barrier(p.flags, bid, tid, rnd++);

  // shared epilogue: partials -> reduce -> gates -> h,c update
  auto epilogue = [&](float acc[4][4], const float* const* bias, float& cc,
                      float* __restrict__ hout) {
    #pragma unroll
    for (int rr = 0; rr < 4; ++rr)
      #pragma unroll
      for (int i2 = 0; i2 < 4; ++i2)
        ub[kt * 520 + (r4 * 4 + rr) * 32 + bg + 8 * i2] = acc[rr][i2];
    __syncthreads();
    {
      const int row = tid >> 5;
      float s = 0.f;
      #pragma unroll
      for (int q = 0; q < 16; ++q) s += ub[q * 520 + tid];
      s += bias[row >> 2][j0 + (row & 3)];
      gs[tid] = s;
    }
    __syncthreads();
    if (tid < 128) {
      const int jl = tid >> 5, bb = tid & 31;
      const int b = bbase + bb;
      const float fg = sigmoidf_(gs[(0 + jl) * 32 + bb]);
      const float ig = sigmoidf_(gs[(4 + jl) * 32 + bb]);
      const float og = sigmoidf_(gs[(8 + jl) * 32 + bb]);
      const float gg = tanhf(gs[(12 + jl) * 32 + bb]);
      cc = fg * cc + ig * gg;
      hout[b * kH + j0 + jl] = og * tanhf(cc);
    }
  };

  // ---------- layer 0: u = [x_t (128) | h0_prev (512)], K=640 ----------
  // chunks: 128 (x), 256, 256
  auto phaseA = [&](int t, const float* __restrict__ h0prev,
                    float* __restrict__ h0out) {
    float4 st[10];
    #pragma unroll
    for (int i = 0; i < 2; ++i) {                       // x chunk
      const int f4 = tid + kThreads * i;
      const int row = f4 >> 5, col = f4 & 31;
      st[i] = *(const float4*)(p.x + ((bbase + row) * kS + t) * kD + col * 4);
    }
    #pragma unroll
    for (int c = 1; c <= 2; ++c)
      #pragma unroll
      for (int i = 0; i < 4; ++i) {                     // h chunks
        const int f4 = tid + kThreads * i;
        const int row = f4 >> 6, col = f4 & 63;
        st[2 + (c - 1) * 4 + i] =
          *(const float4*)(h0prev + (bbase + row) * kH + (c - 1) * 256 + col * 4);
      }

    float acc[4][4];
    #pragma unroll
    for (int a = 0; a < 4; ++a)
      #pragma unroll
      for (int q = 0; q < 4; ++q) acc[a][q] = 0.f;

    const float* wrow[4];
    #pragma unroll
    for (int rr = 0; rr < 4; ++rr)
      wrow[rr] = p.w0[r4] + (j0 + rr) * 640;

    // chunk 0 (x, 128 floats, 2 m-iters)
    {
      float4 wv[2][4];
      #pragma unroll
      for (int m = 0; m < 2; ++m)
        #pragma unroll
        for (int rr = 0; rr < 4; ++rr)
          wv[m][rr] = *(const float4*)(wrow[rr] + (m * 16 + kt) * 4);
      #pragma unroll
      for (int i = 0; i < 2; ++i) {
        const int f4 = tid + kThreads * i;
        const int row = f4 >> 5, col = f4 & 31;
        *(float4*)(ub + row * 260 + col * 4) = st[i];
      }
      __syncthreads();
      #pragma unroll
      for (int m = 0; m < 2; ++m) {
        const int k4 = m * 16 + kt;
        float4 uv[4];
        #pragma unroll
        for (int i2 = 0; i2 < 4; ++i2)
          uv[i2] = *(const float4*)(ub + (bg + 8 * i2) * 260 + k4 * 4);
        #pragma unroll
        for (int rr = 0; rr < 4; ++rr)
          #pragma unroll
          for (int i2 = 0; i2 < 4; ++i2) {
            acc[rr][i2] = fmaf(wv[m][rr].x, uv[i2].x, acc[rr][i2]);
            acc[rr][i2] = fmaf(wv[m][rr].y, uv[i2].y, acc[rr][i2]);
            acc[rr][i2] = fmaf(wv[m][rr].z, uv[i2].z, acc[rr][i2]);
            acc[rr][i2] = fmaf(wv[m][rr].w, uv[i2].w, acc[rr][i2]);
          }
      }
      __syncthreads();
    }
    // chunks 1,2 (256 floats, 4 m-iters each)
    #pragma unroll
    for (int c = 1; c <= 2; ++c) {
      const int kof4 = 32 + (c - 1) * 64;
      float4 wv[4][4];
      #pragma unroll
      for (int m = 0; m < 4; ++m)
        #pragma unroll
        for (int rr = 0; rr < 4; ++rr)
          wv[m][rr] = *(const float4*)(wrow[rr] + (kof4 + m * 16 + kt) * 4);
      #pragma unroll
      for (int i = 0; i < 4; ++i) {
        const int f4 = tid + kThreads * i;
        const int row = f4 >> 6, col = f4 & 63;
        *(float4*)(ub + row * 260 + col * 4) = st[2 + (c - 1) * 4 + i];
      }
      __syncthreads();
      #pragma unroll
      for (int m = 0; m < 4; ++m) {
        const int k4 = m * 16 + kt;
        float4 uv[4];
        #pragma unroll
        for (int i2 = 0; i2 < 4; ++i2)
          uv[i2] = *(const float4*)(ub + (bg + 8 * i2) * 260 + k4 * 4);
        #pragma unroll
        for (int rr = 0; rr < 4; ++rr)
          #pragma unroll
          for (int i2 = 0; i2 < 4; ++i2) {
            acc[rr][i2] = fmaf(wv[m][rr].x, uv[i2].x, acc[rr][i2]);
            acc[rr][i2] = fmaf(wv[m][rr].y, uv[i2].y, acc[rr][i2]);
            acc[rr][i2] = fmaf(wv[m][rr].z, uv[i2].z, acc[rr][i2]);
            acc[rr][i2] = fmaf(wv[m][rr].w, uv[i2].w, acc[rr][i2]);
          }
      }
      __syncthreads();
    }
    const float* bias[4] = { p.b0[0], p.b0[1], p.b0[2], p.b0[3] };
    epilogue(acc, bias, c0, h0out);
  };

  // ---------- layer 1: u = [h0_cur (512) | h1_prev (512)], K=1024 ----------
  // 4 chunks of 256
  auto phaseB = [&](const float* __restrict__ h0cur,
                    const float* __restrict__ h1prev,
                    float* __restrict__ h1out) {
    float4 st[16];
    #pragma unroll
    for (int c = 0; c < 4; ++c)
      #pragma unroll
      for (int i = 0; i < 4; ++i) {
        const int f4 = tid + kThreads * i;
        const int row = f4 >> 6, col = f4 & 63;
        st[c * 4 + i] = (c < 2)
          ? *(const float4*)(h0cur + (bbase + row) * kH + c * 256 + col * 4)
          : *(const float4*)(h1prev + (bbase + row) * kH + (c - 2) * 256 + col * 4);
      }

    float acc[4][4];
    #pragma unroll
    for (int a = 0; a < 4; ++a)
      #pragma unroll
      for (int q = 0; q < 4; ++q) acc[a][q] = 0.f;

    const float* wrow[4];
    #pragma unroll
    for (int rr = 0; rr < 4; ++rr)
      wrow[rr] = p.w1[r4] + (j0 + rr) * 1024;

    #pragma unroll
    for (int c = 0; c < 4; ++c) {
      const int kof4 = c * 64;
      float4 wv[4][4];
      #pragma unroll
      for (int m = 0; m < 4; ++m)
        #pragma unroll
        for (int rr = 0; rr < 4; ++rr)
          wv[m][rr] = *(const float4*)(wrow[rr] + (kof4 + m * 16 + kt) * 4);
      #pragma unroll
      for (int i = 0; i < 4; ++i) {
        const int f4 = tid + kThreads * i;
        const int row = f4 >> 6, col = f4 & 63;
        *(float4*)(ub + row * 260 + col * 4) = st[c * 4 + i];
      }
      __syncthreads();
      #pragma unroll
      for (int m = 0; m < 4; ++m) {
        const int k4 = m * 16 + kt;
        float4 uv[4];
        #pragma unroll
        for (int i2 = 0; i2 < 4; ++i2)
          uv[i2] = *(const float4*)(ub + (bg + 8 * i2) * 260 + k4 * 4);
        #pragma unroll
        for (int rr = 0; rr < 4; ++rr)
          #pragma unroll
          for (int i2 = 0; i2 < 4; ++i2) {
            acc[rr][i2] = fmaf(wv[m][rr].x, uv[i2].x, acc[rr][i2]);
            acc[rr][i2] = fmaf(wv[m][rr].y, uv[i2].y, acc[rr][i2]);
            acc[rr][i2] = fmaf(wv[m][rr].z, uv[i2].z, acc[rr][i2]);
            acc[rr][i2] = fmaf(wv[m][rr].w, uv[i2].w, acc[rr][i2]);
          }
      }
      __syncthreads();
    }
    const float* bias[4] = { p.b1[0], p.b1[1], p.b1[2], p.b1[3] };
    epilogue(acc, bias, c1, h1out);
  };

  // ---------- fused sequence: 1 barrier per step ----------
  phaseA(0, H0buf[1], H0buf[0]);
  grid_barrier(p.flags, bid, tid, rnd++);
  for (int t = 0; t < kS; ++t) {
    phaseB(H0buf[t & 1], H1buf[(t + 1) & 1], H1buf[t & 1]);
    if (t < kS - 1) phaseA(t + 1, H0buf[t & 1], H0buf[(t + 1) & 1]);
    grid_barrier(p.flags, bid, tid, rnd++);
  }

  // ---------- head: fc1 -> fc2 -> relu ----------
  const float* h1f = H1buf[(kS - 1) & 1];
  if (tid < 128) {
    const int jl = tid >> 5, bb = tid & 31;
    const int b = bbase + bb;
    const float* __restrict__ wr = p.fc1w + (j0 + jl) * kH;
    const float* __restrict__ hr = h1f + b * kH;
    float s = p.fc1b[j0 + jl];
    for (int k = 0; k < kH; k += 4) {
      const float4 wv = *(const float4*)(wr + k);
      const float4 hv = *(const float4*)(hr + k);
      s = fmaf(wv.x, hv.x, s); s = fmaf(wv.y, hv.y, s);
      s = fmaf(wv.z, hv.z, s); s = fmaf(wv.w, hv.w, s);
    }
    p.tmp1[b * kH + j0 + jl] = s;
  }
  grid_barrier(p.flags, bid, tid, rnd++);
  if (bid < kOut && tid < kB) {
    const int b = tid;
    const float* __restrict__ wr = p.fc2w + bid * kH;
    const float* __restrict__ tr = p.tmp1 + b * kH;
    float s = p.fc2b[bid];
    for (int k = 0; k < kH; k += 4) {
      const float4 wv = *(const float4*)(wr + k);
      const float4 tv = *(const float4*)(tr + k);
      s = fmaf(wv.x, tv.x, s); s = fmaf(wv.y, tv.y, s);
      s = fmaf(wv.z, tv.z, s); s = fmaf(wv.w, tv.w, s);
    }
    p.out[b * kOut + bid] = fmaxf(s, 0.f);
  }
}

extern "C" void kernel_launch(void* const* d_in, const int* in_sizes, int n_in,
                              void* d_out, int out_size, void* d_ws, size_t ws_size,
                              hipStream_t stream) {
  (void)in_sizes; (void)n_in; (void)out_size; (void)ws_size;
  Params p;
  p.x = (const float*)d_in[0];
  p.w0[0] = (const float*)d_in[1];  p.b0[0] = (const float*)d_in[2];
  p.w0[1] = (const float*)d_in[3];  p.b0[1] = (const float*)d_in[4];
  p.w0[2] = (const float*)d_in[5];  p.b0[2] = (const float*)d_in[6];
  p.w0[3] = (const float*)d_in[7];  p.b0[3] = (const float*)d_in[8];
  p.w1[0] = (const float*)d_in[9];  p.b1[0] = (const float*)d_in[10];
  p.w1[1] = (const float*)d_in[11]; p.b1[1] = (const float*)d_in[12];
  p.w1[2] = (const float*)d_in[13]; p.b1[2] = (const float*)d_in[14];
  p.w1[3] = (const float*)d_in[15]; p.b1[3] = (const float*)d_in[16];
  p.fc1w = (const float*)d_in[17];  p.fc1b = (const float*)d_in[18];
  p.fc2w = (const float*)d_in[19];  p.fc2b = (const float*)d_in[20];

  float* ws = (float*)d_ws;
  p.H0    = ws;                       // 2 * 64*512
  p.H1    = ws + 2 * kB * kH;         // 2 * 64*512
  p.tmp1  = ws + 4 * kB * kH;         // 64*512
  p.flags = (unsigned*)((char*)d_ws + kBarOffBytes);
  p.out   = (float*)d_out;

  // flags/gen must start at 0 (ws is poisoned 0xAA before every launch)
  hipMemsetAsync((char*)d_ws + kBarOffBytes, 0, 20480, stream);

  void* args[] = { &p };
  hipLaunchCooperativeKernel(reinterpret_cast<const void*>(&lstm_persistent),
                             dim3(kBlocks), dim3(kThreads), args, 0, stream);
}

// Round 6
// 23330.946 us; speedup vs baseline: 1.0423x; 1.0423x over previous
//
#include <hip/hip_runtime.h>
#include <cmath>

constexpr int kB = 64, kS = 512, kD = 128, kH = 512, kOut = 24;
constexpr int kBlocks = 256, kThreads = 512;
constexpr size_t kBarOffBytes = (size_t)5 * kB * kH * 4;   // after H0,H1,tmp1

struct Params {
  const float* x;
  const float* w0[4]; const float* b0[4];   // f,i,o,g  [512,640] / [512]
  const float* w1[4]; const float* b1[4];   // f,i,o,g  [512,1024] / [512]
  const float* fc1w; const float* fc1b;
  const float* fc2w; const float* fc2b;
  float* H0;    // 2 buffers [64][512]
  float* H1;    // 2 buffers [64][512]
  float* tmp1;  // [64][512]
  unsigned* flags;  // 256 slots, 64B apart; gen at flags[4096]
  float* out;   // [64][24]
};

__device__ __forceinline__ float sigmoidf_(float v) {
  return 1.0f / (1.0f + expf(-v));
}

// Atomic-free grid barrier (flag/collector). Monotone round numbers, fence-
// to-fence release/acquire via relaxed agent-scope flag stores. No serialized
// same-line RMW chains (round-4 barrier cost ~8us/step from exactly that).
__device__ __forceinline__ void grid_barrier(unsigned* flags, int bid, int tid,
                                             unsigned r) {
  unsigned* gen = flags + 4096;
  __syncthreads();
  if (tid == 0) {
    __threadfence();   // release
    __hip_atomic_store(flags + bid * 16, r + 1u, __ATOMIC_RELAXED,
                       __HIP_MEMORY_SCOPE_AGENT);
  }
  if (bid == 0) {
    if (tid < kBlocks) {
      while (__hip_atomic_load(flags + tid * 16, __ATOMIC_RELAXED,
                               __HIP_MEMORY_SCOPE_AGENT) < r + 1u) {
        __builtin_amdgcn_s_sleep(1);
      }
      __threadfence();  // acquire
    }
    __syncthreads();
    if (tid == 0) {
      __threadfence();
      __hip_atomic_store(gen, r + 1u, __ATOMIC_RELAXED,
                         __HIP_MEMORY_SCOPE_AGENT);
    }
  } else {
    if (tid == 0) {
      while (__hip_atomic_load(gen, __ATOMIC_RELAXED,
                               __HIP_MEMORY_SCOPE_AGENT) < r + 1u) {
        __builtin_amdgcn_s_sleep(1);
      }
      __threadfence();  // acquire
    }
  }
  __syncthreads();
}

// Block (cgi,bh): cols j0=4*cgi..j0+3 (4 gates, 16 rows), batches bh*32..+31.
// Thread tid = r4*128 + kt*8 + bg.
// Pipeline per 128-wide chunk: issue next chunk's staging loads (regs) ->
// ds_write current -> issue current chunk's weight loads -> syncthreads ->
// LDS reads + FMA (no trailing sync; WAR protected by next iter's sync +
// LDS double-buffer). launch_bounds(512,1): 256-VGPR cap (the (512,2) bound
// acted as min-2-blocks/CU -> 128-VGPR cap -> round-5's 45GB scratch spill).
__global__ void __launch_bounds__(kThreads, 1)
lstm_persistent(Params p) {
  __shared__ float ub2[2 * 4224];  // double-buffered u-stage, 32 rows x 132
  __shared__ float part[8320];     // k-split partials, 16 x 520
  __shared__ float gs[512];        // gate preactivations [row(16)][b_local(32)]

  const int tid = threadIdx.x;
  const int bid = blockIdx.x;
  const int cgi = bid >> 1;
  const int bh  = bid & 1;
  const int j0  = cgi * 4;
  const int bbase = bh * 32;

  const int r4 = tid >> 7;
  const int kt = (tid >> 3) & 15;
  const int bg = tid & 7;
  const int r0 = tid >> 5;        // staging row base (f4 = tid + 512*i)
  const int cc0 = tid & 31;       // staging col (f4 units)

  unsigned rnd = 0;

  if (tid < 128) {
    const int jl = tid >> 5, bb = tid & 31;
    const int b = bbase + bb;
    p.H0[kB * kH + b * kH + j0 + jl] = 0.f;
    p.H1[kB * kH + b * kH + j0 + jl] = 0.f;
  }

  float* H0buf[2] = { p.H0, p.H0 + kB * kH };
  float* H1buf[2] = { p.H1, p.H1 + kB * kH };
  float c0s = 0.f, c1s = 0.f;

  grid_barrier(p.flags, bid, tid, rnd++);

  auto epilogue = [&](float acc[4][4], const float* const* bias, float& cc,
                      float* __restrict__ hout) {
    #pragma unroll
    for (int rr = 0; rr < 4; ++rr)
      #pragma unroll
      for (int i2 = 0; i2 < 4; ++i2)
        part[kt * 520 + (r4 * 4 + rr) * 32 + bg + 8 * i2] = acc[rr][i2];
    __syncthreads();
    {
      const int row = tid >> 5;
      float s = 0.f;
      #pragma unroll
      for (int q = 0; q < 16; ++q) s += part[q * 520 + tid];
      s += bias[row >> 2][j0 + (row & 3)];
      gs[tid] = s;
    }
    __syncthreads();
    if (tid < 128) {
      const int jl = tid >> 5, bb = tid & 31;
      const int b = bbase + bb;
      const float fg = sigmoidf_(gs[(0 + jl) * 32 + bb]);
      const float ig = sigmoidf_(gs[(4 + jl) * 32 + bb]);
      const float og = sigmoidf_(gs[(8 + jl) * 32 + bb]);
      const float gg = tanhf(gs[(12 + jl) * 32 + bb]);
      cc = fg * cc + ig * gg;
      hout[b * kH + j0 + jl] = og * tanhf(cc);
    }
  };

  // ---------- layer 0: u = [x_t (128) | h0_prev (512)], K=640, 5 chunks ----
  auto phaseA = [&](int t, const float* __restrict__ h0prev,
                    float* __restrict__ h0out) {
    float acc[4][4];
    #pragma unroll
    for (int a = 0; a < 4; ++a)
      #pragma unroll
      for (int q = 0; q < 4; ++q) acc[a][q] = 0.f;

    const float* wrow[4];
    #pragma unroll
    for (int rr = 0; rr < 4; ++rr)
      wrow[rr] = p.w0[r4] + (j0 + rr) * 640;

    float4 stc[2], stn[2];
    #pragma unroll
    for (int i = 0; i < 2; ++i)   // chunk 0: x_t
      stc[i] = *(const float4*)(p.x + ((bbase + r0 + 16 * i) * kS + t) * kD + cc0 * 4);

    #pragma unroll
    for (int c = 0; c < 5; ++c) {
      if (c < 4)                   // prefetch next chunk (h0_prev)
        #pragma unroll
        for (int i = 0; i < 2; ++i)
          stn[i] = *(const float4*)(h0prev + (bbase + r0 + 16 * i) * kH + c * 128 + cc0 * 4);
      float* buf = ub2 + (c & 1) * 4224;
      #pragma unroll
      for (int i = 0; i < 2; ++i)
        *(float4*)(buf + (r0 + 16 * i) * 132 + cc0 * 4) = stc[i];
      float4 wv[2][4];
      #pragma unroll
      for (int m = 0; m < 2; ++m)
        #pragma unroll
        for (int rr = 0; rr < 4; ++rr)
          wv[m][rr] = *(const float4*)(wrow[rr] + c * 128 + (m * 16 + kt) * 4);
      __syncthreads();
      #pragma unroll
      for (int m = 0; m < 2; ++m) {
        const int k4 = m * 16 + kt;
        float4 uv[4];
        #pragma unroll
        for (int i2 = 0; i2 < 4; ++i2)
          uv[i2] = *(const float4*)(buf + (bg + 8 * i2) * 132 + k4 * 4);
        #pragma unroll
        for (int rr = 0; rr < 4; ++rr)
          #pragma unroll
          for (int i2 = 0; i2 < 4; ++i2) {
            acc[rr][i2] = fmaf(wv[m][rr].x, uv[i2].x, acc[rr][i2]);
            acc[rr][i2] = fmaf(wv[m][rr].y, uv[i2].y, acc[rr][i2]);
            acc[rr][i2] = fmaf(wv[m][rr].z, uv[i2].z, acc[rr][i2]);
            acc[rr][i2] = fmaf(wv[m][rr].w, uv[i2].w, acc[rr][i2]);
          }
      }
      stc[0] = stn[0]; stc[1] = stn[1];
    }
    const float* bias[4] = { p.b0[0], p.b0[1], p.b0[2], p.b0[3] };
    __syncthreads();   // cover last chunk's LDS reads before part writes reuse
    epilogue(acc, bias, c0s, h0out);
  };

  // ---------- layer 1: u = [h0_cur (512) | h1_prev (512)], K=1024, 8 chunks -
  auto phaseB = [&](const float* __restrict__ h0cur,
                    const float* __restrict__ h1prev,
                    float* __restrict__ h1out) {
    float acc[4][4];
    #pragma unroll
    for (int a = 0; a < 4; ++a)
      #pragma unroll
      for (int q = 0; q < 4; ++q) acc[a][q] = 0.f;

    const float* wrow[4];
    #pragma unroll
    for (int rr = 0; rr < 4; ++rr)
      wrow[rr] = p.w1[r4] + (j0 + rr) * 1024;

    float4 stc[2], stn[2];
    #pragma unroll
    for (int i = 0; i < 2; ++i)   // chunk 0: h0_cur
      stc[i] = *(const float4*)(h0cur + (bbase + r0 + 16 * i) * kH + cc0 * 4);

    #pragma unroll
    for (int c = 0; c < 8; ++c) {
      if (c < 7) {
        const int cn = c + 1;
        const float* src = (cn < 4) ? (h0cur + cn * 128) : (h1prev + (cn - 4) * 128);
        #pragma unroll
        for (int i = 0; i < 2; ++i)
          stn[i] = *(const float4*)(src + (bbase + r0 + 16 * i) * kH + cc0 * 4);
      }
      float* buf = ub2 + (c & 1) * 4224;
      #pragma unroll
      for (int i = 0; i < 2; ++i)
        *(float4*)(buf + (r0 + 16 * i) * 132 + cc0 * 4) = stc[i];
      float4 wv[2][4];
      #pragma unroll
      for (int m = 0; m < 2; ++m)
        #pragma unroll
        for (int rr = 0; rr < 4; ++rr)
          wv[m][rr] = *(const float4*)(wrow[rr] + c * 128 + (m * 16 + kt) * 4);
      __syncthreads();
      #pragma unroll
      for (int m = 0; m < 2; ++m) {
        const int k4 = m * 16 + kt;
        float4 uv[4];
        #pragma unroll
        for (int i2 = 0; i2 < 4; ++i2)
          uv[i2] = *(const float4*)(buf + (bg + 8 * i2) * 132 + k4 * 4);
        #pragma unroll
        for (int rr = 0; rr < 4; ++rr)
          #pragma unroll
          for (int i2 = 0; i2 < 4; ++i2) {
            acc[rr][i2] = fmaf(wv[m][rr].x, uv[i2].x, acc[rr][i2]);
            acc[rr][i2] = fmaf(wv[m][rr].y, uv[i2].y, acc[rr][i2]);
            acc[rr][i2] = fmaf(wv[m][rr].z, uv[i2].z, acc[rr][i2]);
            acc[rr][i2] = fmaf(wv[m][rr].w, uv[i2].w, acc[rr][i2]);
          }
      }
      stc[0] = stn[0]; stc[1] = stn[1];
    }
    const float* bias[4] = { p.b1[0], p.b1[1], p.b1[2], p.b1[3] };
    __syncthreads();
    epilogue(acc, bias, c1s, h1out);
  };

  // ---------- fused sequence: 1 barrier per step ----------
  phaseA(0, H0buf[1], H0buf[0]);
  grid_barrier(p.flags, bid, tid, rnd++);
  for (int t = 0; t < kS; ++t) {
    phaseB(H0buf[t & 1], H1buf[(t + 1) & 1], H1buf[t & 1]);
    if (t < kS - 1) phaseA(t + 1, H0buf[t & 1], H0buf[(t + 1) & 1]);
    grid_barrier(p.flags, bid, tid, rnd++);
  }

  // ---------- head: fc1 -> fc2 -> relu ----------
  const float* h1f = H1buf[(kS - 1) & 1];
  if (tid < 128) {
    const int jl = tid >> 5, bb = tid & 31;
    const int b = bbase + bb;
    const float* __restrict__ wr = p.fc1w + (j0 + jl) * kH;
    const float* __restrict__ hr = h1f + b * kH;
    float s = p.fc1b[j0 + jl];
    for (int k = 0; k < kH; k += 4) {
      const float4 wv = *(const float4*)(wr + k);
      const float4 hv = *(const float4*)(hr + k);
      s = fmaf(wv.x, hv.x, s); s = fmaf(wv.y, hv.y, s);
      s = fmaf(wv.z, hv.z, s); s = fmaf(wv.w, hv.w, s);
    }
    p.tmp1[b * kH + j0 + jl] = s;
  }
  grid_barrier(p.flags, bid, tid, rnd++);
  if (bid < kOut && tid < kB) {
    const int b = tid;
    const float* __restrict__ wr = p.fc2w + bid * kH;
    const float* __restrict__ tr = p.tmp1 + b * kH;
    float s = p.fc2b[bid];
    for (int k = 0; k < kH; k += 4) {
      const float4 wv = *(const float4*)(wr + k);
      const float4 tv = *(const float4*)(tr + k);
      s = fmaf(wv.x, tv.x, s); s = fmaf(wv.y, tv.y, s);
      s = fmaf(wv.z, tv.z, s); s = fmaf(wv.w, tv.w, s);
    }
    p.out[b * kOut + bid] = fmaxf(s, 0.f);
  }
}

extern "C" void kernel_launch(void* const* d_in, const int* in_sizes, int n_in,
                              void* d_out, int out_size, void* d_ws, size_t ws_size,
                              hipStream_t stream) {
  (void)in_sizes; (void)n_in; (void)out_size; (void)ws_size;
  Params p;
  p.x = (const float*)d_in[0];
  p.w0[0] = (const float*)d_in[1];  p.b0[0] = (const float*)d_in[2];
  p.w0[1] = (const float*)d_in[3];  p.b0[1] = (const float*)d_in[4];
  p.w0[2] = (const float*)d_in[5];  p.b0[2] = (const float*)d_in[6];
  p.w0[3] = (const float*)d_in[7];  p.b0[3] = (const float*)d_in[8];
  p.w1[0] = (const float*)d_in[9];  p.b1[0] = (const float*)d_in[10];
  p.w1[1] = (const float*)d_in[11]; p.b1[1] = (const float*)d_in[12];
  p.w1[2] = (const float*)d_in[13]; p.b1[2] = (const float*)d_in[14];
  p.w1[3] = (const float*)d_in[15]; p.b1[3] = (const float*)d_in[16];
  p.fc1w = (const float*)d_in[17];  p.fc1b = (const float*)d_in[18];
  p.fc2w = (const float*)d_in[19];  p.fc2b = (const float*)d_in[20];

  float* ws = (float*)d_ws;
  p.H0    = ws;                       // 2 * 64*512
  p.H1    = ws + 2 * kB * kH;         // 2 * 64*512
  p.tmp1  = ws + 4 * kB * kH;         // 64*512
  p.flags = (unsigned*)((char*)d_ws + kBarOffBytes);
  p.out   = (float*)d_out;

  // flags/gen must start at 0 (ws is poisoned 0xAA before every launch)
  hipMemsetAsync((char*)d_ws + kBarOffBytes, 0, 20480, stream);

  void* args[] = { &p };
  hipLaunchCooperativeKernel(reinterpret_cast<const void*>(&lstm_persistent),
                             dim3(kBlocks), dim3(kThreads), args, 0, stream);
}

// Round 7
// 19704.437 us; speedup vs baseline: 1.2342x; 1.1840x over previous
//
#include <hip/hip_runtime.h>
#include <cmath>

constexpr int kB = 64, kS = 512, kD = 128, kH = 512, kOut = 24;
constexpr int kBlocks = 256, kThreads = 512;
constexpr size_t kBarOffBytes = (size_t)5 * kB * kH * 4;   // after H0,H1,tmp1

struct Params {
  const float* x;
  const float* w0[4]; const float* b0[4];   // f,i,o,g  [512,640] / [512]
  const float* w1[4]; const float* b1[4];   // f,i,o,g  [512,1024] / [512]
  const float* fc1w; const float* fc1b;
  const float* fc2w; const float* fc2b;
  float* H0;    // 2 buffers, layout [jg(128)][b(64)][4]
  float* H1;    // 2 buffers, same layout
  float* tmp1;  // [64][512]
  unsigned* flags;  // per half: 128 slots *16 u32 + gen at +2048
  float* out;   // [64][24]
};

__device__ __forceinline__ float sigmoidf_(float v) {
  return 1.0f / (1.0f + expf(-v));
}

// Per-half flag/collector barrier (fan-in 128). Monotone rounds, fence-to-
// fence release/acquire. Collector = rank 0 of the half (bids 0 and 8).
__device__ __forceinline__ void half_barrier(unsigned* flagsH, int rank,
                                             bool isCol, int tid, unsigned r) {
  unsigned* gen = flagsH + 2048;
  __syncthreads();
  if (tid == 0) {
    __threadfence();   // release
    __hip_atomic_store(flagsH + rank * 16, r + 1u, __ATOMIC_RELAXED,
                       __HIP_MEMORY_SCOPE_AGENT);
  }
  if (isCol) {
    if (tid < 128) {
      while (__hip_atomic_load(flagsH + tid * 16, __ATOMIC_RELAXED,
                               __HIP_MEMORY_SCOPE_AGENT) < r + 1u) {
        __builtin_amdgcn_s_sleep(1);
      }
      __threadfence();  // acquire
    }
    __syncthreads();
    if (tid == 0) {
      __threadfence();
      __hip_atomic_store(gen, r + 1u, __ATOMIC_RELAXED,
                         __HIP_MEMORY_SCOPE_AGENT);
    }
  } else {
    if (tid == 0) {
      while (__hip_atomic_load(gen, __ATOMIC_RELAXED,
                               __HIP_MEMORY_SCOPE_AGENT) < r + 1u) {
        __builtin_amdgcn_s_sleep(4);
      }
      __threadfence();  // acquire
    }
  }
  __syncthreads();
}

// Role remap: xcd = bid&7 (round-robin heuristic), s = bid>>3.
// bh = s&1 (batch half), cgi = (bid&7)*16 + (s>>1)  -> the two halves of a
// column-group share an XCD => per-XCD weight set 1.66 MB (L2-resident).
// The two halves are fully independent (all data refs are batch-half-local).
// h layout: h[jg][b][4] (jg = j>>2): block-exclusive contiguous 512B writes.
// Thread tid = r4*128 + kt*8 + bg (gate / 16-way k-split / batch group).
__global__ void __launch_bounds__(kThreads, 1)
lstm_persistent(Params p) {
  __shared__ float ub2[2 * 4224];  // double-buffered u-stage, 32 x 132
  __shared__ float part[8320];     // k-split partials, 16 x 520
  __shared__ float gs[512];        // gate preactivations [row(16)][b(32)]

  const int tid = threadIdx.x;
  const int bid = blockIdx.x;
  const int s   = bid >> 3;
  const int bh  = s & 1;
  const int cgi = (bid & 7) * 16 + (s >> 1);   // 0..127
  const int j0  = cgi * 4;
  const int bbase = bh * 32;
  const int rank = ((bid >> 4) << 3) | (bid & 7);   // 0..127 within half
  const bool isCol = (rank == 0);
  unsigned* flagsH = p.flags + bh * 4096;

  const int r4 = tid >> 7;
  const int kt = (tid >> 3) & 15;
  const int bg = tid & 7;

  unsigned rnd = 0;

  // zero-init buffers read at t=0 (buffer index 1); own 512B region
  if (tid < 128) {
    const int jl = tid >> 5, bb = tid & 31;
    p.H0[kB * kH + cgi * 256 + (bbase + bb) * 4 + jl] = 0.f;
    p.H1[kB * kH + cgi * 256 + (bbase + bb) * 4 + jl] = 0.f;
  }

  float* H0buf[2] = { p.H0, p.H0 + kB * kH };
  float* H1buf[2] = { p.H1, p.H1 + kB * kH };
  float c0s = 0.f, c1s = 0.f;

  half_barrier(flagsH, rank, isCol, tid, rnd); rnd++;

  auto epilogue = [&](float acc[4][4], const float* const* bias, float& cc,
                      float* __restrict__ hout) {
    #pragma unroll
    for (int rr = 0; rr < 4; ++rr)
      #pragma unroll
      for (int i2 = 0; i2 < 4; ++i2)
        part[kt * 520 + (r4 * 4 + rr) * 32 + bg + 8 * i2] = acc[rr][i2];
    __syncthreads();
    {
      const int row = tid >> 5;
      float s2 = 0.f;
      #pragma unroll
      for (int q = 0; q < 16; ++q) s2 += part[q * 520 + tid];
      s2 += bias[row >> 2][j0 + (row & 3)];
      gs[tid] = s2;
    }
    __syncthreads();
    if (tid < 128) {
      const int jl = tid >> 5, bb = tid & 31;
      const float fg = sigmoidf_(gs[(0 + jl) * 32 + bb]);
      const float ig = sigmoidf_(gs[(4 + jl) * 32 + bb]);
      const float og = sigmoidf_(gs[(8 + jl) * 32 + bb]);
      const float gg = tanhf(gs[(12 + jl) * 32 + bb]);
      cc = fg * cc + ig * gg;
      hout[cgi * 256 + (bbase + bb) * 4 + jl] = og * tanhf(cc);
    }
  };

  // FMA inner block for one chunk (identical k-order to rounds 3-6)
  auto chunk_fma = [&](const float* buf, float4 wv[2][4], float acc[4][4]) {
    #pragma unroll
    for (int m = 0; m < 2; ++m) {
      const int k4 = m * 16 + kt;
      float4 uv[4];
      #pragma unroll
      for (int i2 = 0; i2 < 4; ++i2)
        uv[i2] = *(const float4*)(buf + (bg + 8 * i2) * 132 + k4 * 4);
      #pragma unroll
      for (int rr = 0; rr < 4; ++rr)
        #pragma unroll
        for (int i2 = 0; i2 < 4; ++i2) {
          acc[rr][i2] = fmaf(wv[m][rr].x, uv[i2].x, acc[rr][i2]);
          acc[rr][i2] = fmaf(wv[m][rr].y, uv[i2].y, acc[rr][i2]);
          acc[rr][i2] = fmaf(wv[m][rr].z, uv[i2].z, acc[rr][i2]);
          acc[rr][i2] = fmaf(wv[m][rr].w, uv[i2].w, acc[rr][i2]);
        }
    }
  };

  // ---------- layer 0: u = [x_t (128) | h0_prev (512)], 5 chunks ----------
  auto phaseA = [&](int t, const float* __restrict__ h0prev,
                    float* __restrict__ h0out) {
    float acc[4][4];
    #pragma unroll
    for (int a = 0; a < 4; ++a)
      #pragma unroll
      for (int q = 0; q < 4; ++q) acc[a][q] = 0.f;

    const float* wrow[4];
    #pragma unroll
    for (int rr = 0; rr < 4; ++rr)
      wrow[rr] = p.w0[r4] + (j0 + rr) * 640;

    float4 stc[2], stn[2], wvc[2][4], wvn[2][4];
    #pragma unroll
    for (int i = 0; i < 2; ++i) {            // chunk 0: x_t (old lane map)
      const int f4 = tid + kThreads * i;
      const int xb = f4 >> 5, xk = f4 & 31;
      stc[i] = *(const float4*)(p.x + ((bbase + xb) * kS + t) * kD + xk * 4);
    }
    #pragma unroll
    for (int m = 0; m < 2; ++m)
      #pragma unroll
      for (int rr = 0; rr < 4; ++rr)
        wvc[m][rr] = *(const float4*)(wrow[rr] + (m * 16 + kt) * 4);

    #pragma unroll
    for (int c = 0; c < 5; ++c) {
      float* buf = ub2 + (c & 1) * 4224;
      if (c == 0) {
        #pragma unroll
        for (int i = 0; i < 2; ++i) {
          const int f4 = tid + kThreads * i;
          *(float4*)(buf + (f4 >> 5) * 132 + (f4 & 31) * 4) = stc[i];
        }
      } else {
        #pragma unroll
        for (int i = 0; i < 2; ++i) {
          const int f4 = tid + kThreads * i;
          *(float4*)(buf + (f4 & 31) * 132 + (f4 >> 5) * 4) = stc[i];
        }
      }
      if (c < 4) {   // prefetch chunk c+1 (h0prev, jg base 32*c), then weights
        #pragma unroll
        for (int i = 0; i < 2; ++i) {
          const int f4 = tid + kThreads * i;
          const int bl = f4 & 31, kf4 = f4 >> 5;
          stn[i] = *(const float4*)(h0prev + (32 * c + kf4) * 256 +
                                    (bbase + bl) * 4);
        }
        #pragma unroll
        for (int m = 0; m < 2; ++m)
          #pragma unroll
          for (int rr = 0; rr < 4; ++rr)
            wvn[m][rr] = *(const float4*)(wrow[rr] + (c + 1) * 128 +
                                          (m * 16 + kt) * 4);
      }
      __syncthreads();
      chunk_fma(buf, wvc, acc);
      if (c < 4) {
        #pragma unroll
        for (int i = 0; i < 2; ++i) stc[i] = stn[i];
        #pragma unroll
        for (int m = 0; m < 2; ++m)
          #pragma unroll
          for (int rr = 0; rr < 4; ++rr) wvc[m][rr] = wvn[m][rr];
      }
    }
    const float* bias[4] = { p.b0[0], p.b0[1], p.b0[2], p.b0[3] };
    __syncthreads();
    epilogue(acc, bias, c0s, h0out);
  };

  // ---------- layer 1: u = [h0_cur (512) | h1_prev (512)], 8 chunks --------
  auto phaseB = [&](const float* __restrict__ h0cur,
                    const float* __restrict__ h1prev,
                    float* __restrict__ h1out) {
    float acc[4][4];
    #pragma unroll
    for (int a = 0; a < 4; ++a)
      #pragma unroll
      for (int q = 0; q < 4; ++q) acc[a][q] = 0.f;

    const float* wrow[4];
    #pragma unroll
    for (int rr = 0; rr < 4; ++rr)
      wrow[rr] = p.w1[r4] + (j0 + rr) * 1024;

    float4 stc[2], stn[2], wvc[2][4], wvn[2][4];
    #pragma unroll
    for (int i = 0; i < 2; ++i) {            // chunk 0: h0_cur jg 0..31
      const int f4 = tid + kThreads * i;
      const int bl = f4 & 31, kf4 = f4 >> 5;
      stc[i] = *(const float4*)(h0cur + kf4 * 256 + (bbase + bl) * 4);
    }
    #pragma unroll
    for (int m = 0; m < 2; ++m)
      #pragma unroll
      for (int rr = 0; rr < 4; ++rr)
        wvc[m][rr] = *(const float4*)(wrow[rr] + (m * 16 + kt) * 4);

    #pragma unroll
    for (int c = 0; c < 8; ++c) {
      float* buf = ub2 + (c & 1) * 4224;
      #pragma unroll
      for (int i = 0; i < 2; ++i) {
        const int f4 = tid + kThreads * i;
        *(float4*)(buf + (f4 & 31) * 132 + (f4 >> 5) * 4) = stc[i];
      }
      if (c < 7) {
        const int cn = c + 1;
        const float* src = (cn < 4) ? (h0cur + 32 * cn * 256)
                                    : (h1prev + 32 * (cn - 4) * 256);
        #pragma unroll
        for (int i = 0; i < 2; ++i) {
          const int f4 = tid + kThreads * i;
          const int bl = f4 & 31, kf4 = f4 >> 5;
          stn[i] = *(const float4*)(src + kf4 * 256 + (bbase + bl) * 4);
        }
        #pragma unroll
        for (int m = 0; m < 2; ++m)
          #pragma unroll
          for (int rr = 0; rr < 4; ++rr)
            wvn[m][rr] = *(const float4*)(wrow[rr] + cn * 128 +
                                          (m * 16 + kt) * 4);
      }
      __syncthreads();
      chunk_fma(buf, wvc, acc);
      if (c < 7) {
        #pragma unroll
        for (int i = 0; i < 2; ++i) stc[i] = stn[i];
        #pragma unroll
        for (int m = 0; m < 2; ++m)
          #pragma unroll
          for (int rr = 0; rr < 4; ++rr) wvc[m][rr] = wvn[m][rr];
      }
    }
    const float* bias[4] = { p.b1[0], p.b1[1], p.b1[2], p.b1[3] };
    __syncthreads();
    epilogue(acc, bias, c1s, h1out);
  };

  // ---------- fused sequence: 1 half-barrier per step ----------
  phaseA(0, H0buf[1], H0buf[0]);
  half_barrier(flagsH, rank, isCol, tid, rnd); rnd++;
  for (int t = 0; t < kS; ++t) {
    phaseB(H0buf[t & 1], H1buf[(t + 1) & 1], H1buf[t & 1]);
    if (t < kS - 1) phaseA(t + 1, H0buf[t & 1], H0buf[(t + 1) & 1]);
    half_barrier(flagsH, rank, isCol, tid, rnd); rnd++;
  }

  // ---------- head: fc1 -> fc2 -> relu (half-local) ----------
  const float* h1f = H1buf[(kS - 1) & 1];
  if (tid < 128) {
    const int jl = tid >> 5, bb = tid & 31;
    const int b = bbase + bb;
    const float* __restrict__ wr = p.fc1w + (j0 + jl) * kH;
    float s2 = p.fc1b[j0 + jl];
    for (int k = 0; k < kH; k += 4) {
      const float4 wv = *(const float4*)(wr + k);
      const float4 hv = *(const float4*)(h1f + (k >> 2) * 256 + b * 4);
      s2 = fmaf(wv.x, hv.x, s2); s2 = fmaf(wv.y, hv.y, s2);
      s2 = fmaf(wv.z, hv.z, s2); s2 = fmaf(wv.w, hv.w, s2);
    }
    p.tmp1[b * kH + j0 + jl] = s2;
  }
  half_barrier(flagsH, rank, isCol, tid, rnd); rnd++;
  if (cgi < kOut && tid < 32) {
    const int b = bbase + tid;
    const float* __restrict__ wr = p.fc2w + cgi * kH;
    const float* __restrict__ tr = p.tmp1 + b * kH;
    float s2 = p.fc2b[cgi];
    for (int k = 0; k < kH; k += 4) {
      const float4 wv = *(const float4*)(wr + k);
      const float4 tv = *(const float4*)(tr + k);
      s2 = fmaf(wv.x, tv.x, s2); s2 = fmaf(wv.y, tv.y, s2);
      s2 = fmaf(wv.z, tv.z, s2); s2 = fmaf(wv.w, tv.w, s2);
    }
    p.out[b * kOut + cgi] = fmaxf(s2, 0.f);
  }
}

extern "C" void kernel_launch(void* const* d_in, const int* in_sizes, int n_in,
                              void* d_out, int out_size, void* d_ws, size_t ws_size,
                              hipStream_t stream) {
  (void)in_sizes; (void)n_in; (void)out_size; (void)ws_size;
  Params p;
  p.x = (const float*)d_in[0];
  p.w0[0] = (const float*)d_in[1];  p.b0[0] = (const float*)d_in[2];
  p.w0[1] = (const float*)d_in[3];  p.b0[1] = (const float*)d_in[4];
  p.w0[2] = (const float*)d_in[5];  p.b0[2] = (const float*)d_in[6];
  p.w0[3] = (const float*)d_in[7];  p.b0[3] = (const float*)d_in[8];
  p.w1[0] = (const float*)d_in[9];  p.b1[0] = (const float*)d_in[10];
  p.w1[1] = (const float*)d_in[11]; p.b1[1] = (const float*)d_in[12];
  p.w1[2] = (const float*)d_in[13]; p.b1[2] = (const float*)d_in[14];
  p.w1[3] = (const float*)d_in[15]; p.b1[3] = (const float*)d_in[16];
  p.fc1w = (const float*)d_in[17];  p.fc1b = (const float*)d_in[18];
  p.fc2w = (const float*)d_in[19];  p.fc2b = (const float*)d_in[20];

  float* ws = (float*)d_ws;
  p.H0    = ws;                       // 2 * 64*512
  p.H1    = ws + 2 * kB * kH;         // 2 * 64*512
  p.tmp1  = ws + 4 * kB * kH;         // 64*512
  p.flags = (unsigned*)((char*)d_ws + kBarOffBytes);
  p.out   = (float*)d_out;

  // flags/gen must start at 0 (ws is poisoned 0xAA before every launch)
  hipMemsetAsync((char*)d_ws + kBarOffBytes, 0, 36864, stream);

  void* args[] = { &p };
  hipLaunchCooperativeKernel(reinterpret_cast<const void*>(&lstm_persistent),
                             dim3(kBlocks), dim3(kThreads), args, 0, stream);
}